// Round 4
// baseline (268.763 us; speedup 1.0000x reference)
//
#include <hip/hip_runtime.h>
#include <cstdint>
#include <cstddef>

#define B_ 8
#define S_ 1024
#define H_ 8
#define D_ 64
#define DM_ 512

typedef __bf16 bf16x8 __attribute__((ext_vector_type(8)));
typedef float floatx4 __attribute__((ext_vector_type(4)));
typedef unsigned short ushort8 __attribute__((ext_vector_type(8)));
typedef unsigned short ushort4v __attribute__((ext_vector_type(4)));

union Frag { ushort8 us; bf16x8 bf; };

#define MFMA(a, b, c) __builtin_amdgcn_mfma_f32_16x16x32_bf16((a), (b), (c), 0, 0, 0)

__device__ __forceinline__ unsigned short f2bf(float f) {
  unsigned int u = __float_as_uint(f);
  unsigned int r = (u + 0x7fffu + ((u >> 16) & 1u)) >> 16;
  return (unsigned short)r;
}

// async global->LDS, 16B per lane, LDS dest = wave-uniform base + lane*16
__device__ __forceinline__ void gload16(const void* g, void* l) {
  __builtin_amdgcn_global_load_lds(
      (const __attribute__((address_space(1))) unsigned int*)g,
      (__attribute__((address_space(3))) unsigned int*)l, 16, 0, 0);
}

// ---------------------------------------------------------------------------
// prep: [blocks 0..12287] cast q/k/v fp32 -> abf bf16;
//       [blocks 12288..12671] transpose-cast weights -> wt[3072][512] ([n][k]).
// ---------------------------------------------------------------------------
__global__ __launch_bounds__(256) void prep_kernel(
    const float* __restrict__ q, const float* __restrict__ k,
    const float* __restrict__ v, unsigned short* __restrict__ abf,
    const float* __restrict__ Wq, const float* __restrict__ Wk,
    const float* __restrict__ Wv, unsigned short* __restrict__ wt)
{
  __shared__ unsigned short sT[64][72];
  const int tid = threadIdx.x;
  if (blockIdx.x < 12288) {
    size_t i4 = ((size_t)blockIdx.x * 256 + tid) * 4;
    const size_t SEG = (size_t)4 << 20;
    const float* src = (i4 < SEG) ? (q + i4)
                     : (i4 < 2 * SEG) ? (k + (i4 - SEG))
                                      : (v + (i4 - 2 * SEG));
    floatx4 f = *(const floatx4*)src;
    ushort4v o;
    o[0] = f2bf(f[0]); o[1] = f2bf(f[1]); o[2] = f2bf(f[2]); o[3] = f2bf(f[3]);
    *(ushort4v*)(abf + i4) = o;
    return;
  }
  const int bid = blockIdx.x - 12288;     // 0..383
  const int k0 = (bid & 7) * 64;
  const int n0 = (bid >> 3) * 64;
  const float* src; int ncols, nb;
  if (n0 < 1536)      { src = Wq; ncols = 1536; nb = n0; }
  else if (n0 < 2560) { src = Wk; ncols = 1024; nb = n0 - 1536; }
  else                { src = Wv; ncols = 512;  nb = n0 - 2560; }

  const int kr0 = tid >> 4, nc4 = (tid & 15) * 4;
  #pragma unroll
  for (int i = 0; i < 4; i++) {
    int kr = kr0 + i * 16;
    floatx4 f = *(const floatx4*)(src + (size_t)(k0 + kr) * ncols + nb + nc4);
    sT[nc4 + 0][kr] = f2bf(f[0]);
    sT[nc4 + 1][kr] = f2bf(f[1]);
    sT[nc4 + 2][kr] = f2bf(f[2]);
    sT[nc4 + 3][kr] = f2bf(f[3]);
  }
  __syncthreads();
  const int nr0 = tid >> 3, kc8 = (tid & 7) * 8;
  #pragma unroll
  for (int i = 0; i < 2; i++) {
    int nr = nr0 + i * 32;
    *(ushort8*)(wt + (size_t)(n0 + nr) * 512 + k0 + kc8) = *(const ushort8*)&sT[nr][kc8];
  }
}

// ---------------------------------------------------------------------------
// Fused projection GEMM (unchanged from round 3).
// ---------------------------------------------------------------------------
__global__ __launch_bounds__(256) void gemm_kernel(
    const unsigned short* __restrict__ abf, const unsigned short* __restrict__ wt,
    const float* __restrict__ bq, const float* __restrict__ bk,
    const float* __restrict__ bv,
    unsigned short* __restrict__ q1, unsigned short* __restrict__ q2,
    float* __restrict__ gate, unsigned short* __restrict__ k1,
    unsigned short* __restrict__ k2, unsigned short* __restrict__ vT)
{
  const int tid  = threadIdx.x;
  const int wave = tid >> 6;
  const int lane = tid & 63;
  const int l16  = lane & 15;
  const int quad = lane >> 4;
  const int mt = blockIdx.x;
  const int nt = blockIdx.y;
  const int wm = wave & 1, wn = wave >> 1;

  const unsigned short* Asrc =
      abf + (nt < 12 ? 0 : nt < 20 ? ((size_t)4 << 20) : ((size_t)8 << 20));

  __shared__ unsigned short sMem[2 * 128 * 64];
  unsigned short* sA = sMem;
  unsigned short* sB = sMem + 128 * 64;

  floatx4 acc[4][4];
  #pragma unroll
  for (int i = 0; i < 4; i++)
    #pragma unroll
    for (int j = 0; j < 4; j++)
      #pragma unroll
      for (int r = 0; r < 4; r++) acc[i][j][r] = 0.0f;

  const int lrow   = lane >> 3;
  const int lchunk = lane & 7;
  const int gchunk = lchunk ^ lrow;
  const int rkey   = l16 & 7;

  for (int kt = 0; kt < 8; kt++) {
    #pragma unroll
    for (int j = 0; j < 4; j++) {
      int r8 = (wave * 4 + j) * 8;
      gload16(Asrc + (size_t)(mt * 128 + r8 + lrow) * 512 + kt * 64 + gchunk * 8,
              &sA[(wave * 4 + j) * 512]);
      gload16(wt + (size_t)(nt * 128 + r8 + lrow) * 512 + kt * 64 + gchunk * 8,
              &sB[(wave * 4 + j) * 512]);
    }
    __syncthreads();
    #pragma unroll
    for (int c = 0; c < 2; c++) {
      Frag af[4], bf[4];
      #pragma unroll
      for (int mi = 0; mi < 4; mi++)
        af[mi].us = *(const ushort8*)&sA[(wm * 64 + mi * 16 + l16) * 64 +
                                         (((c * 4 + quad) ^ rkey) << 3)];
      #pragma unroll
      for (int ni = 0; ni < 4; ni++)
        bf[ni].us = *(const ushort8*)&sB[(wn * 64 + ni * 16 + l16) * 64 +
                                         (((c * 4 + quad) ^ rkey) << 3)];
      #pragma unroll
      for (int mi = 0; mi < 4; mi++)
        #pragma unroll
        for (int ni = 0; ni < 4; ni++)
          acc[mi][ni] = MFMA(af[mi].bf, bf[ni].bf, acc[mi][ni]);
    }
    __syncthreads();
  }

  const int gm0 = mt * 128 + wm * 64;
  const int bb  = gm0 >> 10;
  const int s0  = gm0 & 1023;
  const int nseg = nt * 2 + wn;
  unsigned short* sC = sMem + wave * 4096;

  int h, sel = 0; bool isV = false;
  const float* bias_arr; int nb0;
  unsigned short* dstb = nullptr;
  if (nseg < 24)      { h = nseg / 3; sel = nseg % 3; bias_arr = bq; nb0 = nseg * 64;
                        dstb = (sel == 0) ? q1 : (sel == 1) ? q2 : nullptr; }
  else if (nseg < 40) { int t = nseg - 24; h = t >> 1; sel = t & 1;
                        bias_arr = bk; nb0 = t * 64; dstb = sel ? k2 : k1; }
  else                { h = nseg - 40; isV = true; bias_arr = bv; nb0 = (nseg - 40) * 64; }

  if (dstb != nullptr || isV) {
    #pragma unroll
    for (int ni = 0; ni < 4; ni++) {
      float bv_ = bias_arr[nb0 + ni * 16 + l16];
      #pragma unroll
      for (int mi = 0; mi < 4; mi++)
        #pragma unroll
        for (int r = 0; r < 4; r++) {
          float val = acc[mi][ni][r] + bv_;
          int ml = mi * 16 + quad * 4 + r;
          int nl = ni * 16 + l16;
          if (!isV) {
            int ch = (nl >> 3) ^ (ml & 7);
            sC[ml * 64 + (ch << 3) + (nl & 7)] = f2bf(val);
          } else {
            int ch = (ml >> 3) ^ (nl & 7);
            sC[nl * 64 + (ch << 3) + (ml & 7)] = f2bf(val);
          }
        }
    }
    const int rr = lane >> 3, cc = lane & 7;
    if (!isV) {
      unsigned short* base = dstb + ((size_t)(bb * H_ + h) * S_ + s0) * D_;
      #pragma unroll
      for (int j = 0; j < 8; j++) {
        int row = j * 8 + rr;
        int logc = cc ^ (row & 7);
        ushort8 valv = *(const ushort8*)&sC[row * 64 + cc * 8];
        *(ushort8*)(base + (size_t)row * D_ + logc * 8) = valv;
      }
    } else {
      unsigned short* base = vT + ((size_t)(bb * H_ + h) * D_) * S_ + s0;
      #pragma unroll
      for (int j = 0; j < 8; j++) {
        int drow = j * 8 + rr;
        int logc = cc ^ (drow & 7);
        ushort8 valv = *(const ushort8*)&sC[drow * 64 + cc * 8];
        *(ushort8*)(base + (size_t)drow * S_ + logc * 8) = valv;
      }
    }
  } else {
    #pragma unroll
    for (int ni = 0; ni < 4; ni++) {
      float bv_ = bias_arr[nb0 + ni * 16 + l16];
      #pragma unroll
      for (int mi = 0; mi < 4; mi++)
        #pragma unroll
        for (int r = 0; r < 4; r++) {
          int s = s0 + mi * 16 + quad * 4 + r;
          int d = ni * 16 + l16;
          gate[((size_t)(bb * H_ + h) * S_ + s) * D_ + d] = acc[mi][ni][r] + bv_;
        }
    }
  }
}

// ---------------------------------------------------------------------------
// Dual-softmax attention: async global_load_lds staging with XOR chunk swizzle
// (unpadded 64x64 K/V arenas), exp2 fold, sP round-trip as round 3.
// ---------------------------------------------------------------------------
__global__ __launch_bounds__(256, 4) void attn_kernel(
    const unsigned short* __restrict__ q1, const unsigned short* __restrict__ q2,
    const unsigned short* __restrict__ k1, const unsigned short* __restrict__ k2,
    const unsigned short* __restrict__ vT, const float* __restrict__ lamp,
    float* __restrict__ O)
{
  const int tid  = threadIdx.x;
  const int wave = tid >> 6;
  const int lane = tid & 63;
  const int l16  = lane & 15;
  const int quad = lane >> 4;
  const int bh = blockIdx.x & 63;
  const int qt = blockIdx.x >> 6;

  __shared__ unsigned short sK1[64 * 64];   // unpadded, XOR-swizzled
  __shared__ unsigned short sK2[64 * 64];
  __shared__ unsigned short sVt[64 * 64];   // [d][key-chunk swizzled]
  __shared__ unsigned short sP [64 * 72];   // padded, r3 scheme

  const int q0 = qt * 64;
  const size_t qoff = ((size_t)bh * S_ + q0 + wave * 16 + l16) * D_;
  Frag qf1[2], qf2[2];
  #pragma unroll
  for (int c = 0; c < 2; c++) {
    qf1[c].us = *(const ushort8*)(q1 + qoff + c * 32 + quad * 8);
    qf2[c].us = *(const ushort8*)(q2 + qoff + c * 32 + quad * 8);
  }

  floatx4 o1[4], o2[4];
  float l1[4], l2[4];
  #pragma unroll
  for (int i = 0; i < 4; i++) {
    #pragma unroll
    for (int j = 0; j < 4; j++) { o1[i][j] = 0.f; o2[i][j] = 0.f; }
    l1[i] = 0.f; l2[i] = 0.f;
  }

  const unsigned short* kb1 = k1 + (size_t)bh * S_ * D_;
  const unsigned short* kb2 = k2 + (size_t)bh * S_ * D_;
  const unsigned short* vb  = vT + (size_t)bh * D_ * S_;

  const int srow = lane >> 3;          // staging row within 8-row chunk
  const int sgch = (lane & 7) ^ srow;  // global chunk (XOR swizzle)
  const int rkey = l16 & 7;            // frag-read swizzle key
  const int prow = wave * 16 + quad * 4;
  const int pq   = (l16 >> 2) & 3;
  const float SCL = 0.18033688011f;    // 0.125 * log2(e)

  for (int kt = 0; kt < 16; kt++) {
    // async staging: wave w stages rows w*16..w*16+15 of each array
    #pragma unroll
    for (int i = 0; i < 2; i++) {
      int r0 = wave * 16 + i * 8;
      gload16(kb1 + (size_t)(kt * 64 + r0 + srow) * 64 + sgch * 8, &sK1[r0 * 64]);
      gload16(kb2 + (size_t)(kt * 64 + r0 + srow) * 64 + sgch * 8, &sK2[r0 * 64]);
      gload16(vb  + (size_t)(r0 + srow) * S_ + kt * 64 + sgch * 8, &sVt[r0 * 64]);
    }
    __syncthreads();

    // ---------- branch 1 ----------
    {
      floatx4 s[4];
      #pragma unroll
      for (int nt = 0; nt < 4; nt++)
        #pragma unroll
        for (int j = 0; j < 4; j++) s[nt][j] = 0.f;
      #pragma unroll
      for (int c = 0; c < 2; c++)
        #pragma unroll
        for (int nt = 0; nt < 4; nt++) {
          Frag kf; kf.us = *(const ushort8*)&sK1[(nt * 16 + l16) * 64 +
                                                 (((c * 4 + quad) ^ rkey) << 3)];
          s[nt] = MFMA(qf1[c].bf, kf.bf, s[nt]);
        }
      #pragma unroll
      for (int nt = 0; nt < 4; nt++)
        #pragma unroll
        for (int r = 0; r < 4; r++) {
          float p = exp2f(s[nt][r] * SCL);
          l1[r] += p;
          sP[(prow + r) * 72 + ((nt ^ quad) << 4) + l16] = f2bf(p);
        }
      #pragma unroll
      for (int c = 0; c < 2; c++) {
        int pg = (c * 2 + (quad >> 1)) ^ pq;
        Frag pa; pa.us = *(const ushort8*)&sP[(wave * 16 + l16) * 72 +
                                              pg * 16 + (quad & 1) * 8];
        #pragma unroll
        for (int dt = 0; dt < 4; dt++) {
          Frag vf; vf.us = *(const ushort8*)&sVt[(dt * 16 + l16) * 64 +
                                                 (((c * 4 + quad) ^ rkey) << 3)];
          o1[dt] = MFMA(pa.bf, vf.bf, o1[dt]);
        }
      }
    }
    // ---------- branch 2 ----------
    {
      floatx4 s[4];
      #pragma unroll
      for (int nt = 0; nt < 4; nt++)
        #pragma unroll
        for (int j = 0; j < 4; j++) s[nt][j] = 0.f;
      #pragma unroll
      for (int c = 0; c < 2; c++)
        #pragma unroll
        for (int nt = 0; nt < 4; nt++) {
          Frag kf; kf.us = *(const ushort8*)&sK2[(nt * 16 + l16) * 64 +
                                                 (((c * 4 + quad) ^ rkey) << 3)];
          s[nt] = MFMA(qf2[c].bf, kf.bf, s[nt]);
        }
      #pragma unroll
      for (int nt = 0; nt < 4; nt++)
        #pragma unroll
        for (int r = 0; r < 4; r++) {
          float p = exp2f(s[nt][r] * SCL);
          l2[r] += p;
          sP[(prow + r) * 72 + ((nt ^ quad) << 4) + l16] = f2bf(p);
        }
      #pragma unroll
      for (int c = 0; c < 2; c++) {
        int pg = (c * 2 + (quad >> 1)) ^ pq;
        Frag pa; pa.us = *(const ushort8*)&sP[(wave * 16 + l16) * 72 +
                                              pg * 16 + (quad & 1) * 8];
        #pragma unroll
        for (int dt = 0; dt < 4; dt++) {
          Frag vf; vf.us = *(const ushort8*)&sVt[(dt * 16 + l16) * 64 +
                                                 (((c * 4 + quad) ^ rkey) << 3)];
          o2[dt] = MFMA(pa.bf, vf.bf, o2[dt]);
        }
      }
    }
    __syncthreads();   // all frag reads done before next kt's staging overwrites
  }

  #pragma unroll
  for (int r = 0; r < 4; r++) {
    #pragma unroll
    for (int off = 1; off < 16; off <<= 1) {
      l1[r] += __shfl_xor(l1[r], off);
      l2[r] += __shfl_xor(l2[r], off);
    }
  }

  const float lam = lamp[0];
  #pragma unroll
  for (int r = 0; r < 4; r++) {
    float i1 = 1.0f / l1[r], i2 = lam / l2[r];
    int row = q0 + wave * 16 + quad * 4 + r;
    #pragma unroll
    for (int dt = 0; dt < 4; dt++) {
      O[((size_t)bh * S_ + row) * D_ + dt * 16 + l16] = o1[dt][r] * i1 - o2[dt][r] * i2;
    }
  }
}

// ---------------------------------------------------------------------------
// Group stats partial sums (unchanged).
// ---------------------------------------------------------------------------
__global__ __launch_bounds__(256) void stats1(const float* __restrict__ O,
                                              float* __restrict__ partial)
{
  const int g = blockIdx.x >> 2, ch = blockIdx.x & 3;
  const int b = g >> 3, j = g & 7;
  const float* base = O + (size_t)b * 8 * 65536;
  float s = 0.f, s2 = 0.f;
  for (int t = threadIdx.x; t < 16384; t += 256) {
    int hh = t >> 11;
    int ss = ch * 256 + ((t >> 3) & 255);
    int r  = t & 7;
    float x = base[(size_t)hh * 65536 + ss * 64 + j * 8 + r];
    s += x; s2 += x * x;
  }
  #pragma unroll
  for (int m = 32; m; m >>= 1) { s += __shfl_down(s, m); s2 += __shfl_down(s2, m); }
  __shared__ float red[8];
  if ((threadIdx.x & 63) == 0) {
    red[(threadIdx.x >> 6) * 2]     = s;
    red[(threadIdx.x >> 6) * 2 + 1] = s2;
  }
  __syncthreads();
  if (threadIdx.x == 0) {
    float S1 = 0.f, S2 = 0.f;
    #pragma unroll
    for (int w = 0; w < 4; w++) { S1 += red[w * 2]; S2 += red[w * 2 + 1]; }
    partial[blockIdx.x * 2]     = S1;
    partial[blockIdx.x * 2 + 1] = S2;
  }
}

// ---------------------------------------------------------------------------
// Epilogue with fused stats combine: normalize, gamma/beta, (1-li),
// sigmoid(gate), output (B,S,H*D).
// ---------------------------------------------------------------------------
__global__ __launch_bounds__(256) void final_kernel(
    const float* __restrict__ O, const float* __restrict__ gate,
    const float* __restrict__ partial, const float* __restrict__ gamma,
    const float* __restrict__ beta, const float* __restrict__ li,
    float* __restrict__ out)
{
  int e = blockIdx.x * 256 + threadIdx.x;
  int d  = e & 63;
  int hh = (e >> 6) & 7;
  int s  = (e >> 9) & 1023;
  int b  = e >> 19;
  size_t oidx = (size_t)(b * 8 + hh) * 65536 + (size_t)s * 64 + d;
  int g = b * 8 + (d >> 3);
  float S1 = 0.f, S2 = 0.f;
  #pragma unroll
  for (int ch = 0; ch < 4; ch++) {
    S1 += partial[(g * 4 + ch) * 2];
    S2 += partial[(g * 4 + ch) * 2 + 1];
  }
  float mean = S1 * (1.0f / 65536.f);
  float inv  = rsqrtf(S2 * (1.0f / 65536.f) - mean * mean + 0.001f);
  float x = (O[oidx] - mean) * inv;
  x = x * gamma[d] + beta[d];
  x *= (1.0f - li[0]);
  float gt = gate[oidx];
  x *= 1.0f / (1.0f + __expf(-gt));
  out[e] = x;
}

extern "C" void kernel_launch(void* const* d_in, const int* in_sizes, int n_in,
                              void* d_out, int out_size, void* d_ws, size_t ws_size,
                              hipStream_t stream)
{
  const float* query  = (const float*)d_in[0];
  const float* key    = (const float*)d_in[1];
  const float* values = (const float*)d_in[2];
  const float* Wq = (const float*)d_in[3];
  const float* bq = (const float*)d_in[4];
  const float* Wk = (const float*)d_in[5];
  const float* bk = (const float*)d_in[6];
  const float* Wv = (const float*)d_in[7];
  const float* bv = (const float*)d_in[8];
  const float* gamma = (const float*)d_in[9];
  const float* beta  = (const float*)d_in[10];
  const float* lam   = (const float*)d_in[11];
  const float* lami  = (const float*)d_in[12];
  float* out = (float*)d_out;

  char* ws = (char*)d_ws;
  const size_t MB = (size_t)1 << 20;
  unsigned short* abf = (unsigned short*)(ws);            // 24 MB
  float*          O   = (float*)(ws);                     // 16 MB, overlays abf
  unsigned short* wt  = (unsigned short*)(ws + 24 * MB);  // 3 MB
  float* partial      = (float*)(ws + 27 * MB);           // 2 KB
  unsigned short* q1  = (unsigned short*)(ws + 28 * MB);
  unsigned short* q2  = (unsigned short*)(ws + 36 * MB);
  unsigned short* k1  = (unsigned short*)(ws + 44 * MB);
  unsigned short* k2  = (unsigned short*)(ws + 52 * MB);
  unsigned short* vT  = (unsigned short*)(ws + 60 * MB);
  float* gate         = (float*)(ws + 68 * MB);           // 16 MB

  prep_kernel<<<12672, 256, 0, stream>>>(query, key, values, abf, Wq, Wk, Wv, wt);
  gemm_kernel<<<dim3(64, 24), 256, 0, stream>>>(abf, wt, bq, bk, bv,
                                                q1, q2, gate, k1, k2, vT);
  attn_kernel<<<dim3(1024), 256, 0, stream>>>(q1, q2, k1, k2, vT, lam, O);
  stats1<<<256, 256, 0, stream>>>(O, partial);
  final_kernel<<<16384, 256, 0, stream>>>(O, gate, partial, gamma, beta, lami, out);
}

// Round 5
// 253.105 us; speedup vs baseline: 1.0619x; 1.0619x over previous
//
#include <hip/hip_runtime.h>
#include <cstdint>
#include <cstddef>

#define B_ 8
#define S_ 1024
#define H_ 8
#define D_ 64
#define DM_ 512

typedef __bf16 bf16x8 __attribute__((ext_vector_type(8)));
typedef float floatx4 __attribute__((ext_vector_type(4)));
typedef unsigned short ushort8 __attribute__((ext_vector_type(8)));
typedef unsigned short ushort4v __attribute__((ext_vector_type(4)));

union Frag { ushort8 us; bf16x8 bf; };
union FragU { uint32_t u[4]; bf16x8 bf; };

#define MFMA(a, b, c) __builtin_amdgcn_mfma_f32_16x16x32_bf16((a), (b), (c), 0, 0, 0)

__device__ __forceinline__ unsigned short f2bf(float f) {
  unsigned int u = __float_as_uint(f);
  unsigned int r = (u + 0x7fffu + ((u >> 16) & 1u)) >> 16;
  return (unsigned short)r;
}

// async global->LDS, 16B per lane, LDS dest = wave-uniform base + lane*16
__device__ __forceinline__ void gload16(const void* g, void* l) {
  __builtin_amdgcn_global_load_lds(
      (const __attribute__((address_space(1))) unsigned int*)g,
      (__attribute__((address_space(3))) unsigned int*)l, 16, 0, 0);
}

// ---------------------------------------------------------------------------
// prep: [blocks 0..12287] cast q/k/v fp32 -> abf bf16;
//       [blocks 12288..12671] transpose-cast weights -> wt[3072][512] ([n][k]).
// ---------------------------------------------------------------------------
__global__ __launch_bounds__(256) void prep_kernel(
    const float* __restrict__ q, const float* __restrict__ k,
    const float* __restrict__ v, unsigned short* __restrict__ abf,
    const float* __restrict__ Wq, const float* __restrict__ Wk,
    const float* __restrict__ Wv, unsigned short* __restrict__ wt)
{
  __shared__ unsigned short sT[64][72];
  const int tid = threadIdx.x;
  if (blockIdx.x < 12288) {
    size_t i4 = ((size_t)blockIdx.x * 256 + tid) * 4;
    const size_t SEG = (size_t)4 << 20;
    const float* src = (i4 < SEG) ? (q + i4)
                     : (i4 < 2 * SEG) ? (k + (i4 - SEG))
                                      : (v + (i4 - 2 * SEG));
    floatx4 f = *(const floatx4*)src;
    ushort4v o;
    o[0] = f2bf(f[0]); o[1] = f2bf(f[1]); o[2] = f2bf(f[2]); o[3] = f2bf(f[3]);
    *(ushort4v*)(abf + i4) = o;
    return;
  }
  const int bid = blockIdx.x - 12288;     // 0..383
  const int k0 = (bid & 7) * 64;
  const int n0 = (bid >> 3) * 64;
  const float* src; int ncols, nb;
  if (n0 < 1536)      { src = Wq; ncols = 1536; nb = n0; }
  else if (n0 < 2560) { src = Wk; ncols = 1024; nb = n0 - 1536; }
  else                { src = Wv; ncols = 512;  nb = n0 - 2560; }

  const int kr0 = tid >> 4, nc4 = (tid & 15) * 4;
  #pragma unroll
  for (int i = 0; i < 4; i++) {
    int kr = kr0 + i * 16;
    floatx4 f = *(const floatx4*)(src + (size_t)(k0 + kr) * ncols + nb + nc4);
    sT[nc4 + 0][kr] = f2bf(f[0]);
    sT[nc4 + 1][kr] = f2bf(f[1]);
    sT[nc4 + 2][kr] = f2bf(f[2]);
    sT[nc4 + 3][kr] = f2bf(f[3]);
  }
  __syncthreads();
  const int nr0 = tid >> 3, kc8 = (tid & 7) * 8;
  #pragma unroll
  for (int i = 0; i < 2; i++) {
    int nr = nr0 + i * 32;
    *(ushort8*)(wt + (size_t)(n0 + nr) * 512 + k0 + kc8) = *(const ushort8*)&sT[nr][kc8];
  }
}

// ---------------------------------------------------------------------------
// Fused projection GEMM (unchanged from round 3/4).
// ---------------------------------------------------------------------------
__global__ __launch_bounds__(256) void gemm_kernel(
    const unsigned short* __restrict__ abf, const unsigned short* __restrict__ wt,
    const float* __restrict__ bq, const float* __restrict__ bk,
    const float* __restrict__ bv,
    unsigned short* __restrict__ q1, unsigned short* __restrict__ q2,
    float* __restrict__ gate, unsigned short* __restrict__ k1,
    unsigned short* __restrict__ k2, unsigned short* __restrict__ vT)
{
  const int tid  = threadIdx.x;
  const int wave = tid >> 6;
  const int lane = tid & 63;
  const int l16  = lane & 15;
  const int quad = lane >> 4;
  const int mt = blockIdx.x;
  const int nt = blockIdx.y;
  const int wm = wave & 1, wn = wave >> 1;

  const unsigned short* Asrc =
      abf + (nt < 12 ? 0 : nt < 20 ? ((size_t)4 << 20) : ((size_t)8 << 20));

  __shared__ unsigned short sMem[2 * 128 * 64];
  unsigned short* sA = sMem;
  unsigned short* sB = sMem + 128 * 64;

  floatx4 acc[4][4];
  #pragma unroll
  for (int i = 0; i < 4; i++)
    #pragma unroll
    for (int j = 0; j < 4; j++)
      #pragma unroll
      for (int r = 0; r < 4; r++) acc[i][j][r] = 0.0f;

  const int lrow   = lane >> 3;
  const int lchunk = lane & 7;
  const int gchunk = lchunk ^ lrow;
  const int rkey   = l16 & 7;

  for (int kt = 0; kt < 8; kt++) {
    #pragma unroll
    for (int j = 0; j < 4; j++) {
      int r8 = (wave * 4 + j) * 8;
      gload16(Asrc + (size_t)(mt * 128 + r8 + lrow) * 512 + kt * 64 + gchunk * 8,
              &sA[(wave * 4 + j) * 512]);
      gload16(wt + (size_t)(nt * 128 + r8 + lrow) * 512 + kt * 64 + gchunk * 8,
              &sB[(wave * 4 + j) * 512]);
    }
    __syncthreads();
    #pragma unroll
    for (int c = 0; c < 2; c++) {
      Frag af[4], bf[4];
      #pragma unroll
      for (int mi = 0; mi < 4; mi++)
        af[mi].us = *(const ushort8*)&sA[(wm * 64 + mi * 16 + l16) * 64 +
                                         (((c * 4 + quad) ^ rkey) << 3)];
      #pragma unroll
      for (int ni = 0; ni < 4; ni++)
        bf[ni].us = *(const ushort8*)&sB[(wn * 64 + ni * 16 + l16) * 64 +
                                         (((c * 4 + quad) ^ rkey) << 3)];
      #pragma unroll
      for (int mi = 0; mi < 4; mi++)
        #pragma unroll
        for (int ni = 0; ni < 4; ni++)
          acc[mi][ni] = MFMA(af[mi].bf, bf[ni].bf, acc[mi][ni]);
    }
    __syncthreads();
  }

  const int gm0 = mt * 128 + wm * 64;
  const int bb  = gm0 >> 10;
  const int s0  = gm0 & 1023;
  const int nseg = nt * 2 + wn;
  unsigned short* sC = sMem + wave * 4096;

  int h, sel = 0; bool isV = false;
  const float* bias_arr; int nb0;
  unsigned short* dstb = nullptr;
  if (nseg < 24)      { h = nseg / 3; sel = nseg % 3; bias_arr = bq; nb0 = nseg * 64;
                        dstb = (sel == 0) ? q1 : (sel == 1) ? q2 : nullptr; }
  else if (nseg < 40) { int t = nseg - 24; h = t >> 1; sel = t & 1;
                        bias_arr = bk; nb0 = t * 64; dstb = sel ? k2 : k1; }
  else                { h = nseg - 40; isV = true; bias_arr = bv; nb0 = (nseg - 40) * 64; }

  if (dstb != nullptr || isV) {
    #pragma unroll
    for (int ni = 0; ni < 4; ni++) {
      float bv_ = bias_arr[nb0 + ni * 16 + l16];
      #pragma unroll
      for (int mi = 0; mi < 4; mi++)
        #pragma unroll
        for (int r = 0; r < 4; r++) {
          float val = acc[mi][ni][r] + bv_;
          int ml = mi * 16 + quad * 4 + r;
          int nl = ni * 16 + l16;
          if (!isV) {
            int ch = (nl >> 3) ^ (ml & 7);
            sC[ml * 64 + (ch << 3) + (nl & 7)] = f2bf(val);
          } else {
            int ch = (ml >> 3) ^ (nl & 7);
            sC[nl * 64 + (ch << 3) + (ml & 7)] = f2bf(val);
          }
        }
    }
    const int rr = lane >> 3, cc = lane & 7;
    if (!isV) {
      unsigned short* base = dstb + ((size_t)(bb * H_ + h) * S_ + s0) * D_;
      #pragma unroll
      for (int j = 0; j < 8; j++) {
        int row = j * 8 + rr;
        int logc = cc ^ (row & 7);
        ushort8 valv = *(const ushort8*)&sC[row * 64 + cc * 8];
        *(ushort8*)(base + (size_t)row * D_ + logc * 8) = valv;
      }
    } else {
      unsigned short* base = vT + ((size_t)(bb * H_ + h) * D_) * S_ + s0;
      #pragma unroll
      for (int j = 0; j < 8; j++) {
        int drow = j * 8 + rr;
        int logc = cc ^ (drow & 7);
        ushort8 valv = *(const ushort8*)&sC[drow * 64 + cc * 8];
        *(ushort8*)(base + (size_t)drow * S_ + logc * 8) = valv;
      }
    }
  } else {
    #pragma unroll
    for (int ni = 0; ni < 4; ni++) {
      float bv_ = bias_arr[nb0 + ni * 16 + l16];
      #pragma unroll
      for (int mi = 0; mi < 4; mi++)
        #pragma unroll
        for (int r = 0; r < 4; r++) {
          int s = s0 + mi * 16 + quad * 4 + r;
          int d = ni * 16 + l16;
          gate[((size_t)(bb * H_ + h) * S_ + s) * D_ + d] = acc[mi][ni][r] + bv_;
        }
    }
  }
}

// ---------------------------------------------------------------------------
// Dual-softmax attention, transposed form: S^T = mfma(K,Q) (D[key][q]),
// P^T built in-register via cross-lane shuffles (no sP LDS round-trip),
// O^T = mfma(V^T, P^T) (D[d][q]); shared V-frag reads across branches;
// O^T re-coalesced through LDS once per block. l is per-lane scalar.
// ---------------------------------------------------------------------------
__global__ __launch_bounds__(256, 4) void attn_kernel(
    const unsigned short* __restrict__ q1, const unsigned short* __restrict__ q2,
    const unsigned short* __restrict__ k1, const unsigned short* __restrict__ k2,
    const unsigned short* __restrict__ vT, const float* __restrict__ lamp,
    float* __restrict__ O)
{
  const int tid  = threadIdx.x;
  const int wave = tid >> 6;
  const int lane = tid & 63;
  const int l16  = lane & 15;
  const int quad = lane >> 4;
  const int bh = blockIdx.x & 63;
  const int qt = blockIdx.x >> 6;

  __shared__ unsigned short sMem[3 * 4096];   // sK1 | sK2 | sVt (24 KB)
  unsigned short* sK1 = sMem;
  unsigned short* sK2 = sMem + 4096;
  unsigned short* sVt = sMem + 8192;

  const int q0 = qt * 64;
  const size_t qoff = ((size_t)bh * S_ + q0 + wave * 16 + l16) * D_;
  Frag qf1[2], qf2[2];
  #pragma unroll
  for (int c = 0; c < 2; c++) {
    qf1[c].us = *(const ushort8*)(q1 + qoff + c * 32 + quad * 8);
    qf2[c].us = *(const ushort8*)(q2 + qoff + c * 32 + quad * 8);
  }

  floatx4 o1t[4], o2t[4];          // O^T: lane holds d=dt*16+quad*4+r, q=l16
  float l1 = 0.f, l2 = 0.f;        // per-lane (one q per lane)
  #pragma unroll
  for (int i = 0; i < 4; i++)
    #pragma unroll
    for (int j = 0; j < 4; j++) { o1t[i][j] = 0.f; o2t[i][j] = 0.f; }

  const unsigned short* kb1 = k1 + (size_t)bh * S_ * D_;
  const unsigned short* kb2 = k2 + (size_t)bh * S_ * D_;
  const unsigned short* vb  = vT + (size_t)bh * D_ * S_;

  const int srow = lane >> 3;          // staging row within 8-row chunk
  const int sgch = (lane & 7) ^ srow;  // global chunk (XOR swizzle)
  const int rkey = l16 & 7;            // frag-read swizzle key

  for (int kt = 0; kt < 16; kt++) {
    // async staging: wave w stages rows w*16..w*16+15 of each array
    #pragma unroll
    for (int i = 0; i < 2; i++) {
      int r0 = wave * 16 + i * 8;
      gload16(kb1 + (size_t)(kt * 64 + r0 + srow) * 64 + sgch * 8, &sK1[r0 * 64]);
      gload16(kb2 + (size_t)(kt * 64 + r0 + srow) * 64 + sgch * 8, &sK2[r0 * 64]);
      gload16(vb  + (size_t)(r0 + srow) * S_ + kt * 64 + sgch * 8, &sVt[r0 * 64]);
    }
    __syncthreads();

    // S^T = mfma(A=K, B=Q): D[m=key][n=q]
    floatx4 s1[4], s2[4];
    #pragma unroll
    for (int nt = 0; nt < 4; nt++)
      #pragma unroll
      for (int j = 0; j < 4; j++) { s1[nt][j] = 0.f; s2[nt][j] = 0.f; }
    #pragma unroll
    for (int c = 0; c < 2; c++)
      #pragma unroll
      for (int nt = 0; nt < 4; nt++) {
        Frag kf1; kf1.us = *(const ushort8*)&sK1[(nt * 16 + l16) * 64 +
                                                 (((c * 4 + quad) ^ rkey) << 3)];
        s1[nt] = MFMA(kf1.bf, qf1[c].bf, s1[nt]);
        Frag kf2; kf2.us = *(const ushort8*)&sK2[(nt * 16 + l16) * 64 +
                                                 (((c * 4 + quad) ^ rkey) << 3)];
        s2[nt] = MFMA(kf2.bf, qf2[c].bf, s2[nt]);
      }

    // exp + pack pairs (r, r+1) -> u32 of 2 bf16
    uint32_t pk1[4][2], pk2[4][2];
    #pragma unroll
    for (int nt = 0; nt < 4; nt++)
      #pragma unroll
      for (int h = 0; h < 2; h++) {
        float a1 = __expf(s1[nt][2 * h]     * 0.125f);
        float b1v = __expf(s1[nt][2 * h + 1] * 0.125f);
        l1 += a1 + b1v;
        pk1[nt][h] = (uint32_t)f2bf(a1) | ((uint32_t)f2bf(b1v) << 16);
        float a2 = __expf(s2[nt][2 * h]     * 0.125f);
        float b2v = __expf(s2[nt][2 * h + 1] * 0.125f);
        l2 += a2 + b2v;
        pk2[nt][h] = (uint32_t)f2bf(a2) | ((uint32_t)f2bf(b2v) << 16);
      }

    // O^T += mfma(A=V^T, B=P^T); P^T B-frag via shuffles:
    // slot p holds keys c*32+quad*8+{2p,2p+1}; source lane (l16, (2*quad+(p>>1))&3),
    // source register pk[c*2 + (quad>>1)][p&1]  (quad = target's quad).
    #pragma unroll
    for (int c = 0; c < 2; c++) {
      FragU b1, b2;
      #pragma unroll
      for (int p = 0; p < 4; p++) {
        int src = l16 + ((((quad << 1) + (p >> 1)) & 3) << 4);
        int h = p & 1;
        int lo1 = __shfl((int)pk1[c * 2][h],     src, 64);
        int hi1 = __shfl((int)pk1[c * 2 + 1][h], src, 64);
        b1.u[p] = (quad & 2) ? (uint32_t)hi1 : (uint32_t)lo1;
        int lo2 = __shfl((int)pk2[c * 2][h],     src, 64);
        int hi2 = __shfl((int)pk2[c * 2 + 1][h], src, 64);
        b2.u[p] = (quad & 2) ? (uint32_t)hi2 : (uint32_t)lo2;
      }
      #pragma unroll
      for (int dt = 0; dt < 4; dt++) {
        Frag vf; vf.us = *(const ushort8*)&sVt[(dt * 16 + l16) * 64 +
                                               (((c * 4 + quad) ^ rkey) << 3)];
        o1t[dt] = MFMA(vf.bf, b1.bf, o1t[dt]);
        o2t[dt] = MFMA(vf.bf, b2.bf, o2t[dt]);
      }
    }
    __syncthreads();   // all frag reads done before next kt's staging overwrites
  }

  // l: sum across the 4 quads (keys partitioned by quad rows)
  l1 += __shfl_xor(l1, 16, 64); l1 += __shfl_xor(l1, 32, 64);
  l2 += __shfl_xor(l2, 16, 64); l2 += __shfl_xor(l2, 32, 64);

  const float lam = lamp[0];
  const float i1 = 1.0f / l1;
  const float i2 = lam / l2;

  // stage O^T (fp32) into dead K arenas, padded rows; then coalesced writeback
  float* fO = (float*)sMem;   // needs 64*65*4 = 16640 B <= 24576 B
  #pragma unroll
  for (int dt = 0; dt < 4; dt++)
    #pragma unroll
    for (int r = 0; r < 4; r++) {
      int d = dt * 16 + quad * 4 + r;
      fO[d * 65 + wave * 16 + l16] = o1t[dt][r] * i1 - o2t[dt][r] * i2;
    }
  __syncthreads();

  float* Ob = O + ((size_t)bh * S_ + q0) * D_;
  #pragma unroll
  for (int i = 0; i < 4; i++) {
    int qrow = i * 16 + (tid >> 4);
    int d0 = (tid & 15) * 4;
    floatx4 v;
    #pragma unroll
    for (int j = 0; j < 4; j++) v[j] = fO[(d0 + j) * 65 + qrow];
    *(floatx4*)(Ob + (size_t)qrow * D_ + d0) = v;
  }
}

// ---------------------------------------------------------------------------
// Group stats partial sums (unchanged).
// ---------------------------------------------------------------------------
__global__ __launch_bounds__(256) void stats1(const float* __restrict__ O,
                                              float* __restrict__ partial)
{
  const int g = blockIdx.x >> 2, ch = blockIdx.x & 3;
  const int b = g >> 3, j = g & 7;
  const float* base = O + (size_t)b * 8 * 65536;
  float s = 0.f, s2 = 0.f;
  for (int t = threadIdx.x; t < 16384; t += 256) {
    int hh = t >> 11;
    int ss = ch * 256 + ((t >> 3) & 255);
    int r  = t & 7;
    float x = base[(size_t)hh * 65536 + ss * 64 + j * 8 + r];
    s += x; s2 += x * x;
  }
  #pragma unroll
  for (int m = 32; m; m >>= 1) { s += __shfl_down(s, m); s2 += __shfl_down(s2, m); }
  __shared__ float red[8];
  if ((threadIdx.x & 63) == 0) {
    red[(threadIdx.x >> 6) * 2]     = s;
    red[(threadIdx.x >> 6) * 2 + 1] = s2;
  }
  __syncthreads();
  if (threadIdx.x == 0) {
    float S1 = 0.f, S2 = 0.f;
    #pragma unroll
    for (int w = 0; w < 4; w++) { S1 += red[w * 2]; S2 += red[w * 2 + 1]; }
    partial[blockIdx.x * 2]     = S1;
    partial[blockIdx.x * 2 + 1] = S2;
  }
}

// ---------------------------------------------------------------------------
// Epilogue with fused stats combine (unchanged).
// ---------------------------------------------------------------------------
__global__ __launch_bounds__(256) void final_kernel(
    const float* __restrict__ O, const float* __restrict__ gate,
    const float* __restrict__ partial, const float* __restrict__ gamma,
    const float* __restrict__ beta, const float* __restrict__ li,
    float* __restrict__ out)
{
  int e = blockIdx.x * 256 + threadIdx.x;
  int d  = e & 63;
  int hh = (e >> 6) & 7;
  int s  = (e >> 9) & 1023;
  int b  = e >> 19;
  size_t oidx = (size_t)(b * 8 + hh) * 65536 + (size_t)s * 64 + d;
  int g = b * 8 + (d >> 3);
  float S1 = 0.f, S2 = 0.f;
  #pragma unroll
  for (int ch = 0; ch < 4; ch++) {
    S1 += partial[(g * 4 + ch) * 2];
    S2 += partial[(g * 4 + ch) * 2 + 1];
  }
  float mean = S1 * (1.0f / 65536.f);
  float inv  = rsqrtf(S2 * (1.0f / 65536.f) - mean * mean + 0.001f);
  float x = (O[oidx] - mean) * inv;
  x = x * gamma[d] + beta[d];
  x *= (1.0f - li[0]);
  float gt = gate[oidx];
  x *= 1.0f / (1.0f + __expf(-gt));
  out[e] = x;
}

extern "C" void kernel_launch(void* const* d_in, const int* in_sizes, int n_in,
                              void* d_out, int out_size, void* d_ws, size_t ws_size,
                              hipStream_t stream)
{
  const float* query  = (const float*)d_in[0];
  const float* key    = (const float*)d_in[1];
  const float* values = (const float*)d_in[2];
  const float* Wq = (const float*)d_in[3];
  const float* bq = (const float*)d_in[4];
  const float* Wk = (const float*)d_in[5];
  const float* bk = (const float*)d_in[6];
  const float* Wv = (const float*)d_in[7];
  const float* bv = (const float*)d_in[8];
  const float* gamma = (const float*)d_in[9];
  const float* beta  = (const float*)d_in[10];
  const float* lam   = (const float*)d_in[11];
  const float* lami  = (const float*)d_in[12];
  float* out = (float*)d_out;

  char* ws = (char*)d_ws;
  const size_t MB = (size_t)1 << 20;
  unsigned short* abf = (unsigned short*)(ws);            // 24 MB
  float*          O   = (float*)(ws);                     // 16 MB, overlays abf
  unsigned short* wt  = (unsigned short*)(ws + 24 * MB);  // 3 MB
  float* partial      = (float*)(ws + 27 * MB);           // 2 KB
  unsigned short* q1  = (unsigned short*)(ws + 28 * MB);
  unsigned short* q2  = (unsigned short*)(ws + 36 * MB);
  unsigned short* k1  = (unsigned short*)(ws + 44 * MB);
  unsigned short* k2  = (unsigned short*)(ws + 52 * MB);
  unsigned short* vT  = (unsigned short*)(ws + 60 * MB);
  float* gate         = (float*)(ws + 68 * MB);           // 16 MB

  prep_kernel<<<12672, 256, 0, stream>>>(query, key, values, abf, Wq, Wk, Wv, wt);
  gemm_kernel<<<dim3(64, 24), 256, 0, stream>>>(abf, wt, bq, bk, bv,
                                                q1, q2, gate, k1, k2, vT);
  attn_kernel<<<dim3(1024), 256, 0, stream>>>(q1, q2, k1, k2, vT, lam, O);
  stats1<<<256, 256, 0, stream>>>(O, partial);
  final_kernel<<<16384, 256, 0, stream>>>(O, gate, partial, gamma, beta, lami, out);
}

// Round 6
// 242.915 us; speedup vs baseline: 1.1064x; 1.0419x over previous
//
#include <hip/hip_runtime.h>
#include <cstdint>
#include <cstddef>

#define B_ 8
#define S_ 1024
#define H_ 8
#define D_ 64
#define DM_ 512

typedef __bf16 bf16x8 __attribute__((ext_vector_type(8)));
typedef float floatx4 __attribute__((ext_vector_type(4)));
typedef float floatx16 __attribute__((ext_vector_type(16)));
typedef unsigned short ushort8 __attribute__((ext_vector_type(8)));
typedef unsigned short ushort4v __attribute__((ext_vector_type(4)));

union Frag { ushort8 us; bf16x8 bf; };

#define MFMA16(a, b, c) __builtin_amdgcn_mfma_f32_16x16x32_bf16((a), (b), (c), 0, 0, 0)
#define MFMA32(a, b, c) __builtin_amdgcn_mfma_f32_32x32x16_bf16((a), (b), (c), 0, 0, 0)

__device__ __forceinline__ unsigned short f2bf(float f) {
  unsigned int u = __float_as_uint(f);
  unsigned int r = (u + 0x7fffu + ((u >> 16) & 1u)) >> 16;
  return (unsigned short)r;
}

// async global->LDS, 16B per lane, LDS dest = wave-uniform base + lane*16
__device__ __forceinline__ void gload16(const void* g, void* l) {
  __builtin_amdgcn_global_load_lds(
      (const __attribute__((address_space(1))) unsigned int*)g,
      (__attribute__((address_space(3))) unsigned int*)l, 16, 0, 0);
}

// ---------------------------------------------------------------------------
// prep: [0..12287] cast q/k/v fp32 -> abf bf16; [12288..12671] transpose-cast
// weights -> wt[3072][512]; [12672] zero the 128-float stats accumulator.
// ---------------------------------------------------------------------------
__global__ __launch_bounds__(256) void prep_kernel(
    const float* __restrict__ q, const float* __restrict__ k,
    const float* __restrict__ v, unsigned short* __restrict__ abf,
    const float* __restrict__ Wq, const float* __restrict__ Wk,
    const float* __restrict__ Wv, unsigned short* __restrict__ wt,
    float* __restrict__ partial)
{
  __shared__ unsigned short sT[64][72];
  const int tid = threadIdx.x;
  if (blockIdx.x < 12288) {
    size_t i4 = ((size_t)blockIdx.x * 256 + tid) * 4;
    const size_t SEG = (size_t)4 << 20;
    const float* src = (i4 < SEG) ? (q + i4)
                     : (i4 < 2 * SEG) ? (k + (i4 - SEG))
                                      : (v + (i4 - 2 * SEG));
    floatx4 f = *(const floatx4*)src;
    ushort4v o;
    o[0] = f2bf(f[0]); o[1] = f2bf(f[1]); o[2] = f2bf(f[2]); o[3] = f2bf(f[3]);
    *(ushort4v*)(abf + i4) = o;
    return;
  }
  if (blockIdx.x == 12672) {
    if (tid < 128) partial[tid] = 0.f;
    return;
  }
  const int bid = blockIdx.x - 12288;     // 0..383
  const int k0 = (bid & 7) * 64;
  const int n0 = (bid >> 3) * 64;
  const float* src; int ncols, nb;
  if (n0 < 1536)      { src = Wq; ncols = 1536; nb = n0; }
  else if (n0 < 2560) { src = Wk; ncols = 1024; nb = n0 - 1536; }
  else                { src = Wv; ncols = 512;  nb = n0 - 2560; }

  const int kr0 = tid >> 4, nc4 = (tid & 15) * 4;
  #pragma unroll
  for (int i = 0; i < 4; i++) {
    int kr = kr0 + i * 16;
    floatx4 f = *(const floatx4*)(src + (size_t)(k0 + kr) * ncols + nb + nc4);
    sT[nc4 + 0][kr] = f2bf(f[0]);
    sT[nc4 + 1][kr] = f2bf(f[1]);
    sT[nc4 + 2][kr] = f2bf(f[2]);
    sT[nc4 + 3][kr] = f2bf(f[3]);
  }
  __syncthreads();
  const int nr0 = tid >> 3, kc8 = (tid & 7) * 8;
  #pragma unroll
  for (int i = 0; i < 2; i++) {
    int nr = nr0 + i * 32;
    *(ushort8*)(wt + (size_t)(n0 + nr) * 512 + k0 + kc8) = *(const ushort8*)&sT[nr][kc8];
  }
}

// ---------------------------------------------------------------------------
// Fused projection GEMM (round-3 structure; q1/q2 now pre-scaled by 1/8).
// ---------------------------------------------------------------------------
__global__ __launch_bounds__(256) void gemm_kernel(
    const unsigned short* __restrict__ abf, const unsigned short* __restrict__ wt,
    const float* __restrict__ bq, const float* __restrict__ bk,
    const float* __restrict__ bv,
    unsigned short* __restrict__ q1, unsigned short* __restrict__ q2,
    float* __restrict__ gate, unsigned short* __restrict__ k1,
    unsigned short* __restrict__ k2, unsigned short* __restrict__ vT)
{
  const int tid  = threadIdx.x;
  const int wave = tid >> 6;
  const int lane = tid & 63;
  const int l16  = lane & 15;
  const int quad = lane >> 4;
  const int mt = blockIdx.x;
  const int nt = blockIdx.y;
  const int wm = wave & 1, wn = wave >> 1;

  const unsigned short* Asrc =
      abf + (nt < 12 ? 0 : nt < 20 ? ((size_t)4 << 20) : ((size_t)8 << 20));

  __shared__ unsigned short sMem[2 * 128 * 64];
  unsigned short* sA = sMem;
  unsigned short* sB = sMem + 128 * 64;

  floatx4 acc[4][4];
  #pragma unroll
  for (int i = 0; i < 4; i++)
    #pragma unroll
    for (int j = 0; j < 4; j++)
      #pragma unroll
      for (int r = 0; r < 4; r++) acc[i][j][r] = 0.0f;

  const int lrow   = lane >> 3;
  const int gchunk = (lane & 7) ^ lrow;
  const int rkey   = l16 & 7;

  for (int kt = 0; kt < 8; kt++) {
    #pragma unroll
    for (int j = 0; j < 4; j++) {
      int r8 = (wave * 4 + j) * 8;
      gload16(Asrc + (size_t)(mt * 128 + r8 + lrow) * 512 + kt * 64 + gchunk * 8,
              &sA[(wave * 4 + j) * 512]);
      gload16(wt + (size_t)(nt * 128 + r8 + lrow) * 512 + kt * 64 + gchunk * 8,
              &sB[(wave * 4 + j) * 512]);
    }
    __syncthreads();
    #pragma unroll
    for (int c = 0; c < 2; c++) {
      Frag af[4], bf[4];
      #pragma unroll
      for (int mi = 0; mi < 4; mi++)
        af[mi].us = *(const ushort8*)&sA[(wm * 64 + mi * 16 + l16) * 64 +
                                         (((c * 4 + quad) ^ rkey) << 3)];
      #pragma unroll
      for (int ni = 0; ni < 4; ni++)
        bf[ni].us = *(const ushort8*)&sB[(wn * 64 + ni * 16 + l16) * 64 +
                                         (((c * 4 + quad) ^ rkey) << 3)];
      #pragma unroll
      for (int mi = 0; mi < 4; mi++)
        #pragma unroll
        for (int ni = 0; ni < 4; ni++)
          acc[mi][ni] = MFMA16(af[mi].bf, bf[ni].bf, acc[mi][ni]);
    }
    __syncthreads();
  }

  const int gm0 = mt * 128 + wm * 64;
  const int bb  = gm0 >> 10;
  const int s0  = gm0 & 1023;
  const int nseg = nt * 2 + wn;
  unsigned short* sC = sMem + wave * 4096;

  int h, sel = 0; bool isV = false;
  const float* bias_arr; int nb0;
  unsigned short* dstb = nullptr;
  if (nseg < 24)      { h = nseg / 3; sel = nseg % 3; bias_arr = bq; nb0 = nseg * 64;
                        dstb = (sel == 0) ? q1 : (sel == 1) ? q2 : nullptr; }
  else if (nseg < 40) { int t = nseg - 24; h = t >> 1; sel = t & 1;
                        bias_arr = bk; nb0 = t * 64; dstb = sel ? k2 : k1; }
  else                { h = nseg - 40; isV = true; bias_arr = bv; nb0 = (nseg - 40) * 64; }

  if (dstb != nullptr || isV) {
    const float scl = (nseg < 24) ? 0.125f : 1.0f;   // fold 1/sqrt(DK) into q1,q2
    #pragma unroll
    for (int ni = 0; ni < 4; ni++) {
      float bv_ = bias_arr[nb0 + ni * 16 + l16];
      #pragma unroll
      for (int mi = 0; mi < 4; mi++)
        #pragma unroll
        for (int r = 0; r < 4; r++) {
          float val = (acc[mi][ni][r] + bv_) * scl;
          int ml = mi * 16 + quad * 4 + r;
          int nl = ni * 16 + l16;
          if (!isV) {
            int ch = (nl >> 3) ^ (ml & 7);
            sC[ml * 64 + (ch << 3) + (nl & 7)] = f2bf(val);
          } else {
            int ch = (ml >> 3) ^ (nl & 7);
            sC[nl * 64 + (ch << 3) + (ml & 7)] = f2bf(val);
          }
        }
    }
    const int rr = lane >> 3, cc = lane & 7;
    if (!isV) {
      unsigned short* base = dstb + ((size_t)(bb * H_ + h) * S_ + s0) * D_;
      #pragma unroll
      for (int j = 0; j < 8; j++) {
        int row = j * 8 + rr;
        int logc = cc ^ (row & 7);
        ushort8 valv = *(const ushort8*)&sC[row * 64 + cc * 8];
        *(ushort8*)(base + (size_t)row * D_ + logc * 8) = valv;
      }
    } else {
      unsigned short* base = vT + ((size_t)(bb * H_ + h) * D_) * S_ + s0;
      #pragma unroll
      for (int j = 0; j < 8; j++) {
        int drow = j * 8 + rr;
        int logc = cc ^ (drow & 7);
        ushort8 valv = *(const ushort8*)&sC[drow * 64 + cc * 8];
        *(ushort8*)(base + (size_t)drow * S_ + logc * 8) = valv;
      }
    }
  } else {
    #pragma unroll
    for (int ni = 0; ni < 4; ni++) {
      float bv_ = bias_arr[nb0 + ni * 16 + l16];
      #pragma unroll
      for (int mi = 0; mi < 4; mi++)
        #pragma unroll
        for (int r = 0; r < 4; r++) {
          int s = s0 + mi * 16 + quad * 4 + r;
          int d = ni * 16 + l16;
          gate[((size_t)(bb * H_ + h) * S_ + s) * D_ + d] = acc[mi][ni][r] + bv_;
        }
    }
  }
}

// ---------------------------------------------------------------------------
// Dual-softmax attention on 32x32x16 MFMA. Wave w=(kh,qh) owns the
// [kh*32 keys x qh*32 q] S^T tile and the [kh*32 d x qh*32 q] O^T tile.
// Q B-frags preloaded (q1/q2 pre-scaled by 1/8). P round-trips via
// XOR-swizzled sP: packed b32 writes, conflict-free b128 B-frag reads
// (same phys-chunk formula as the V A-frag reads). Group-stats partials
// fused into the epilogue (shuffle + LDS-atomic + 16 global atomics).
// LDS = 5 x 8KB = 40960 B -> 4 blocks/CU.
// ---------------------------------------------------------------------------
__global__ __launch_bounds__(256, 4) void attn_kernel(
    const unsigned short* __restrict__ q1, const unsigned short* __restrict__ q2,
    const unsigned short* __restrict__ k1, const unsigned short* __restrict__ k2,
    const unsigned short* __restrict__ vT, const float* __restrict__ lamp,
    float* __restrict__ O, float* __restrict__ partial)
{
  const int tid   = threadIdx.x;
  const int wave  = tid >> 6;
  const int lane  = tid & 63;
  const int l32   = lane & 31;
  const int lhalf = lane >> 5;
  const int kh    = wave & 1;      // key/d half
  const int qh    = wave >> 1;     // q half
  const int bh = blockIdx.x & 63;
  const int qt = blockIdx.x >> 6;
  const int q0 = qt * 64;

  __shared__ unsigned short sMem[5 * 4096];   // sK1|sK2|sVt|sP1|sP2, 40960 B
  unsigned short* sK1 = sMem;
  unsigned short* sK2 = sMem + 4096;
  unsigned short* sVt = sMem + 8192;
  unsigned short* sP1 = sMem + 12288;
  unsigned short* sP2 = sMem + 16384;

  // Q B-frags: B[k][n]: n=q=qh*32+l32, k=ks*16+lhalf*8+j
  const size_t qrowoff = ((size_t)bh * S_ + q0 + qh * 32 + l32) * D_ + lhalf * 8;
  Frag qb1[4], qb2[4];
  #pragma unroll
  for (int ks = 0; ks < 4; ks++) {
    qb1[ks].us = *(const ushort8*)(q1 + qrowoff + ks * 16);
    qb2[ks].us = *(const ushort8*)(q2 + qrowoff + ks * 16);
  }

  floatx16 o1, o2;
  #pragma unroll
  for (int r = 0; r < 16; r++) { o1[r] = 0.f; o2[r] = 0.f; }
  float l1 = 0.f, l2 = 0.f;

  const unsigned short* kb1 = k1 + (size_t)bh * S_ * D_;
  const unsigned short* kb2 = k2 + (size_t)bh * S_ * D_;
  const unsigned short* vb  = vT + (size_t)bh * D_ * S_;

  const int srow = lane >> 3;          // staging row within 8-row group
  const int sgch = (lane & 7) ^ srow;  // fetched logical chunk (XOR swizzle)
  const int akey = l32 & 7;            // frag-read swizzle key
  const int mrow = kh * 32 + l32;      // this wave's key/d row

  for (int kt = 0; kt < 16; kt++) {
    #pragma unroll
    for (int i = 0; i < 2; i++) {
      int r0 = wave * 16 + i * 8;
      gload16(kb1 + (size_t)(kt * 64 + r0 + srow) * 64 + sgch * 8, &sK1[r0 * 64]);
      gload16(kb2 + (size_t)(kt * 64 + r0 + srow) * 64 + sgch * 8, &sK2[r0 * 64]);
      gload16(vb  + (size_t)(r0 + srow) * S_ + kt * 64 + sgch * 8, &sVt[r0 * 64]);
    }
    __syncthreads();

    // S^T tiles (both branches share the loop; A=K frags, B=Q regs)
    floatx16 s1, s2;
    #pragma unroll
    for (int r = 0; r < 16; r++) { s1[r] = 0.f; s2[r] = 0.f; }
    #pragma unroll
    for (int ks = 0; ks < 4; ks++) {
      int phys = ((ks * 2 + lhalf) ^ akey) << 3;
      Frag kf1; kf1.us = *(const ushort8*)&sK1[mrow * 64 + phys];
      s1 = MFMA32(kf1.bf, qb1[ks].bf, s1);
      Frag kf2; kf2.us = *(const ushort8*)&sK2[mrow * 64 + phys];
      s2 = MFMA32(kf2.bf, qb2[ks].bf, s2);
    }

    // exp + packed P writes (C-layout reg pairs = adjacent keys)
    const int qrow = (qh * 32 + l32) * 64;
    #pragma unroll
    for (int p = 0; p < 8; p++) {
      int key = kh * 32 + 2 * (p & 1) + 8 * (p >> 1) + 4 * lhalf;
      int addr = qrow + (((key >> 3) ^ akey) << 3) + (key & 7);
      float a1 = __expf(s1[2 * p]), b1 = __expf(s1[2 * p + 1]);
      l1 += a1 + b1;
      *(uint32_t*)&sP1[addr] = (uint32_t)f2bf(a1) | ((uint32_t)f2bf(b1) << 16);
      float a2 = __expf(s2[2 * p]), b2 = __expf(s2[2 * p + 1]);
      l2 += a2 + b2;
      *(uint32_t*)&sP2[addr] = (uint32_t)f2bf(a2) | ((uint32_t)f2bf(b2) << 16);
    }
    __syncthreads();

    // O^T += V^T @ P^T  (A=V frags shared across branches; B=P frags)
    #pragma unroll
    for (int ks = 0; ks < 4; ks++) {
      int phys = ((ks * 2 + lhalf) ^ akey) << 3;
      Frag vf; vf.us = *(const ushort8*)&sVt[mrow * 64 + phys];
      Frag pf1; pf1.us = *(const ushort8*)&sP1[qrow + phys];
      o1 = MFMA32(vf.bf, pf1.bf, o1);
      Frag pf2; pf2.us = *(const ushort8*)&sP2[qrow + phys];
      o2 = MFMA32(vf.bf, pf2.bf, o2);
    }
    __syncthreads();
  }

  // ---- epilogue: l reduce, normalize, coalesced O write, fused stats ----
  l1 += __shfl_xor(l1, 32, 64);
  l2 += __shfl_xor(l2, 32, 64);
  float* sL = (float*)(sMem + 10240);   // bytes 20480..21504 (inside dead sVt)
  float* sG = (float*)(sMem + 10752);   // bytes 21504..21568
  if (lane < 32) {
    sL[(0 * 2 + kh) * 64 + qh * 32 + l32] = l1;
    sL[(1 * 2 + kh) * 64 + qh * 32 + l32] = l2;
  }
  __syncthreads();

  const int q = qh * 32 + l32;
  float i1 = 1.0f / (sL[q] + sL[64 + q]);
  float i2 = lamp[0] / (sL[128 + q] + sL[192 + q]);
  float* fO = (float*)sMem;             // bytes 0..16640 (dead sK1/sK2/sVt head)
  #pragma unroll
  for (int r = 0; r < 16; r++) {
    int d = kh * 32 + (r & 3) + 8 * (r >> 2) + 4 * lhalf;
    fO[d * 65 + q] = o1[r] * i1 - o2[r] * i2;
  }
  if (tid < 16) sG[tid] = 0.f;
  __syncthreads();

  float ss = 0.f, ss2 = 0.f;
  float* Ob = O + ((size_t)bh * S_ + q0) * D_;
  #pragma unroll
  for (int i = 0; i < 4; i++) {
    int qrw = i * 16 + (tid >> 4);
    int d0 = (tid & 15) * 4;
    floatx4 v;
    #pragma unroll
    for (int j = 0; j < 4; j++) {
      v[j] = fO[(d0 + j) * 65 + qrw];
      ss += v[j]; ss2 += v[j] * v[j];
    }
    *(floatx4*)(Ob + (size_t)qrw * D_ + d0) = v;
  }
  // reduce lanes sharing the same j-group ((lane&15)>>1)
  ss  += __shfl_xor(ss, 16, 64);  ss  += __shfl_xor(ss, 32, 64);  ss  += __shfl_xor(ss, 1, 64);
  ss2 += __shfl_xor(ss2, 16, 64); ss2 += __shfl_xor(ss2, 32, 64); ss2 += __shfl_xor(ss2, 1, 64);
  if (lane < 16 && (lane & 1) == 0) {
    int j = lane >> 1;
    atomicAdd(&sG[j * 2],     ss);
    atomicAdd(&sG[j * 2 + 1], ss2);
  }
  __syncthreads();
  if (tid < 16) atomicAdd(&partial[(bh >> 3) * 16 + tid], sG[tid]);
}

// ---------------------------------------------------------------------------
// Epilogue: normalize with fused-accumulated stats, gamma/beta, (1-li),
// sigmoid(gate), output (B,S,H*D).
// ---------------------------------------------------------------------------
__global__ __launch_bounds__(256) void final_kernel(
    const float* __restrict__ O, const float* __restrict__ gate,
    const float* __restrict__ partial, const float* __restrict__ gamma,
    const float* __restrict__ beta, const float* __restrict__ li,
    float* __restrict__ out)
{
  int e = blockIdx.x * 256 + threadIdx.x;
  int d  = e & 63;
  int hh = (e >> 6) & 7;
  int s  = (e >> 9) & 1023;
  int b  = e >> 19;
  size_t oidx = (size_t)(b * 8 + hh) * 65536 + (size_t)s * 64 + d;
  int g = b * 8 + (d >> 3);
  float S1 = partial[g * 2];
  float S2 = partial[g * 2 + 1];
  float mean = S1 * (1.0f / 65536.f);
  float inv  = rsqrtf(S2 * (1.0f / 65536.f) - mean * mean + 0.001f);
  float x = (O[oidx] - mean) * inv;
  x = x * gamma[d] + beta[d];
  x *= (1.0f - li[0]);
  float gt = gate[oidx];
  x *= 1.0f / (1.0f + __expf(-gt));
  out[e] = x;
}

extern "C" void kernel_launch(void* const* d_in, const int* in_sizes, int n_in,
                              void* d_out, int out_size, void* d_ws, size_t ws_size,
                              hipStream_t stream)
{
  const float* query  = (const float*)d_in[0];
  const float* key    = (const float*)d_in[1];
  const float* values = (const float*)d_in[2];
  const float* Wq = (const float*)d_in[3];
  const float* bq = (const float*)d_in[4];
  const float* Wk = (const float*)d_in[5];
  const float* bk = (const float*)d_in[6];
  const float* Wv = (const float*)d_in[7];
  const float* bv = (const float*)d_in[8];
  const float* gamma = (const float*)d_in[9];
  const float* beta  = (const float*)d_in[10];
  const float* lam   = (const float*)d_in[11];
  const float* lami  = (const float*)d_in[12];
  float* out = (float*)d_out;

  char* ws = (char*)d_ws;
  const size_t MB = (size_t)1 << 20;
  unsigned short* abf = (unsigned short*)(ws);            // 24 MB
  float*          O   = (float*)(ws);                     // 16 MB, overlays abf
  unsigned short* wt  = (unsigned short*)(ws + 24 * MB);  // 3 MB
  float* partial      = (float*)(ws + 27 * MB);           // 512 B
  unsigned short* q1  = (unsigned short*)(ws + 28 * MB);
  unsigned short* q2  = (unsigned short*)(ws + 36 * MB);
  unsigned short* k1  = (unsigned short*)(ws + 44 * MB);
  unsigned short* k2  = (unsigned short*)(ws + 52 * MB);
  unsigned short* vT  = (unsigned short*)(ws + 60 * MB);
  float* gate         = (float*)(ws + 68 * MB);           // 16 MB

  prep_kernel<<<12673, 256, 0, stream>>>(query, key, values, abf, Wq, Wk, Wv, wt,
                                         partial);
  gemm_kernel<<<dim3(64, 24), 256, 0, stream>>>(abf, wt, bq, bk, bv,
                                                q1, q2, gate, k1, k2, vT);
  attn_kernel<<<dim3(1024), 256, 0, stream>>>(q1, q2, k1, k2, vT, lam, O, partial);
  final_kernel<<<16384, 256, 0, stream>>>(O, gate, partial, gamma, beta, lami, out);
}